// Round 6
// baseline (539.333 us; speedup 1.0000x reference)
//
#include <hip/hip_runtime.h>

#define N_ATOMS 100000
#define M_NBRS 12
#define ATOM_F 64
#define NBR_F 41
#define OUT_DIM 128   // 2*ATOM_F
#define IN_DIM 169    // 2*ATOM_F + NBR_F
#define N_GROUPS (N_ATOMS / 16)   // 6250, exact

typedef __attribute__((ext_vector_type(8))) short short8;
typedef __attribute__((ext_vector_type(4))) float f32x4;
typedef __attribute__((ext_vector_type(4))) unsigned u32x4;

// packed f32x2 -> bf16x2 (RNE): lo16 = bf16(a), hi16 = bf16(b). 1 VALU inst.
__device__ __forceinline__ unsigned cvt_pk(float a, float b) {
    unsigned r;
    asm("v_cvt_pk_bf16_f32 %0, %1, %2" : "=v"(r) : "v"(a), "v"(b));
    return r;
}
__device__ __forceinline__ float softplus_f(float x) {
    return fmaxf(x, 0.f) + __logf(1.f + __expf(-fabsf(x)));
}
__device__ __forceinline__ float sigmoid_f(float x) {
    return __fdividef(1.f, 1.f + __expf(-x));
}

// ---------------------------------------------------------------------------
// P: per-atom precompute, one 16-atom tile per wave, NO per-tile LDS.
//   abf[a*32 + kk*16 + g*4 + t] = bf16 pair (features kk*32+g*8+2t, +1)
//   A1P[grp*1024 + r4*256 + l*4 + nt] = u32{ lo=bf16((Wself·a+b)[nt*16+c]),
//        hi=bf16(...[64+nt*16+c]) } for row g*4+r4 — producer lane and
//        consumer lane are the SAME lane index -> both sides coalesced b128.
// W_self fragments staged frag-linear in LDS (16 KB, conflict-free).
// ---------------------------------------------------------------------------
__global__ __launch_bounds__(256, 4) void k_prep(
    const float* __restrict__ atom, const float* __restrict__ W,
    const float* __restrict__ bias, unsigned* __restrict__ abf_u32,
    unsigned* __restrict__ A1P, float* __restrict__ SUM)
{
    __shared__ __align__(16) unsigned BFp[16 * 64 * 4];   // 16 KB
    const int tid = threadIdx.x;
    const int w = tid >> 6, l = tid & 63;
    const int r = l & 15, g = l >> 4;

    if (blockIdx.x == 0 && tid < 128) SUM[tid] = 0.f;

    // stage W_self fragments: 16 frags x 64 lanes, 4 slots per thread
    #pragma unroll
    for (int s = 0; s < 4; ++s) {
        int f = s * 4 + w;              // frag = nt*2 + kk
        int nt = f >> 1, kk = f & 1;
        int col = nt * 16 + r;
        int kbase = kk * 32 + g * 8;
        const float* wp = W + col * IN_DIM + kbase;   // k < 64 always valid
        u32x4 pk;
        pk[0] = cvt_pk(wp[0], wp[1]); pk[1] = cvt_pk(wp[2], wp[3]);
        pk[2] = cvt_pk(wp[4], wp[5]); pk[3] = cvt_pk(wp[6], wp[7]);
        *reinterpret_cast<u32x4*>(&BFp[(f * 64 + l) * 4]) = pk;
    }
    __syncthreads();

    const int gw = blockIdx.x * 4 + w;
    if (gw >= N_GROUPS) return;
    const int base = gw * 16;

    float bb[8];
    #pragma unroll
    for (int nt = 0; nt < 8; ++nt) bb[nt] = bias[nt * 16 + r];

    // A fragments: 8 contiguous, 16B-aligned floats per (lane, kk)
    union { u32x4 u; short8 s; } af[2];
    #pragma unroll
    for (int kk = 0; kk < 2; ++kk) {
        const float4* ap = reinterpret_cast<const float4*>(atom)
                           + (size_t)(base + r) * 16 + kk * 8 + g * 2;
        float4 v0 = ap[0], v1 = ap[1];
        af[kk].u[0] = cvt_pk(v0.x, v0.y); af[kk].u[1] = cvt_pk(v0.z, v0.w);
        af[kk].u[2] = cvt_pk(v1.x, v1.y); af[kk].u[3] = cvt_pk(v1.z, v1.w);
        *reinterpret_cast<u32x4*>(&abf_u32[(size_t)(base + r) * 32 + kk * 16 + g * 4])
            = af[kk].u;
    }

    // MFMA: filter (nt) and core (nt+4), pack into A1P lane layout
    u32x4 outp[4];   // [r4][nt]
    #pragma unroll
    for (int nt = 0; nt < 4; ++nt) {
        f32x4 accf = {0.f,0.f,0.f,0.f}, accc = {0.f,0.f,0.f,0.f};
        #pragma unroll
        for (int kk = 0; kk < 2; ++kk) {
            union { u32x4 u; short8 s; } uf, uc;
            uf.u = *reinterpret_cast<const u32x4*>(&BFp[((nt * 2 + kk) * 64 + l) * 4]);
            uc.u = *reinterpret_cast<const u32x4*>(&BFp[(((nt + 4) * 2 + kk) * 64 + l) * 4]);
            accf = __builtin_amdgcn_mfma_f32_16x16x32_bf16(af[kk].s, uf.s, accf, 0,0,0);
            accc = __builtin_amdgcn_mfma_f32_16x16x32_bf16(af[kk].s, uc.s, accc, 0,0,0);
        }
        #pragma unroll
        for (int r4 = 0; r4 < 4; ++r4)
            outp[r4][nt] = cvt_pk(accf[r4] + bb[nt], accc[r4] + bb[nt + 4]);
    }
    #pragma unroll
    for (int r4 = 0; r4 < 4; ++r4)
        *reinterpret_cast<u32x4*>(&A1P[(size_t)gw * 1024 + r4 * 256 + l * 4]) = outp[r4];
}

// ---------------------------------------------------------------------------
// M: one 16-atom group per wave, 12 MFMA tiles (one per neighbor slot),
// A-fragments straight from global (no A-LDS, no ds round-trip; round-4:
// bank conflicts 0).  B fragments frag-linear in LDS (32 KB, conflict-free);
// opaque-asm blocks LICM (hoisting 32 b128 would pin 128 VGPRs).
// ROUND-5: (a) launch_bounds(256,5) — LDS 32KBx5 = 160KB exactly, 5
// blocks/CU = 62.5% occupancy cap (round-4 was latency-bound at 2.8
// waves/SIMD); (b) a1 unpack hoisted out of the m-loop (was ~770 redundant
// VALU/group); VGPR est ~90 < 102 cap.
// BN partial stats fused (128 atomics per block).
// ---------------------------------------------------------------------------
struct EBuf { unsigned p2[4]; unsigned p3[4]; };   // packed bf16 edge frags

__device__ __forceinline__ EBuf load_edges(const float* __restrict__ ep, int g)
{
    EBuf b;
    float v[8];
    #pragma unroll
    for (int j = 0; j < 8; ++j) v[j] = ep[g * 8 + j];      // floats 0..31
    b.p2[0] = cvt_pk(v[0], v[1]); b.p2[1] = cvt_pk(v[2], v[3]);
    b.p2[2] = cvt_pk(v[4], v[5]); b.p2[3] = cvt_pk(v[6], v[7]);
    b.p3[0] = b.p3[1] = b.p3[2] = b.p3[3] = 0u;
    if (g == 0) {
        float u[8];
        #pragma unroll
        for (int j = 0; j < 8; ++j) u[j] = ep[32 + j];     // floats 32..39
        b.p3[0] = cvt_pk(u[0], u[1]); b.p3[1] = cvt_pk(u[2], u[3]);
        b.p3[2] = cvt_pk(u[4], u[5]); b.p3[3] = cvt_pk(u[6], u[7]);
    } else if (g == 1) {
        b.p3[0] = cvt_pk(ep[40], 0.f);                     // float 40, pad 41
    }
    return b;
}

__global__ __launch_bounds__(256, 5) void k_msg(
    const float* __restrict__ atom, const float* __restrict__ nbr,
    const float* __restrict__ W, const int* __restrict__ idx,
    const unsigned* __restrict__ abf, const unsigned* __restrict__ A1P,
    float* __restrict__ X, float* __restrict__ SUM)
{
    __shared__ __align__(16) unsigned BF[32 * 64 * 4];   // 32 KB, frag-linear
    const int tid = threadIdx.x;
    const int w = tid >> 6, l = tid & 63;
    const int c = l & 15, g = l >> 4;

    // stage W_msg fragments: 32 frags x 64 lanes, 8 slots per thread.
    #pragma unroll
    for (int s = 0; s < 8; ++s) {
        int f = s * 4 + w;
        int nt = f >> 2, kk = f & 3;
        int col = nt * 16 + c;
        int kbase = kk * 32 + g * 8;
        const float* wp = W + col * IN_DIM + 64 + kbase;
        u32x4 pk;
        float v[8];
        #pragma unroll
        for (int j = 0; j < 8; ++j)
            v[j] = (kbase + j < 105) ? wp[j] : 0.f;        // K-pad 105..127
        pk[0] = cvt_pk(v[0], v[1]); pk[1] = cvt_pk(v[2], v[3]);
        pk[2] = cvt_pk(v[4], v[5]); pk[3] = cvt_pk(v[6], v[7]);
        *reinterpret_cast<u32x4*>(&BF[(f * 64 + l) * 4]) = pk;
    }
    __syncthreads();

    const int gw = blockIdx.x * 4 + w;
    float sum_p[4] = {0.f,0.f,0.f,0.f}, sq_p[4] = {0.f,0.f,0.f,0.f};

    if (gw < N_GROUPS) {
        const int base = gw * 16;
        // A1: load packed pairs (coalesced b128), unpack ONCE to f32 regs
        float a1f[4][4], a1c[4][4];
        #pragma unroll
        for (int r4 = 0; r4 < 4; ++r4) {
            u32x4 q = *reinterpret_cast<const u32x4*>(
                &A1P[(size_t)gw * 1024 + r4 * 256 + l * 4]);
            #pragma unroll
            for (int p = 0; p < 4; ++p) {
                a1f[r4][p] = __uint_as_float(q[p] << 16);
                a1c[r4][p] = __uint_as_float(q[p] & 0xffff0000u);
            }
        }

        float gs[4][4];
        #pragma unroll
        for (int r4 = 0; r4 < 4; ++r4)
          #pragma unroll
          for (int p = 0; p < 4; ++p) gs[r4][p] = 0.f;

        const int irow = (base + c) * M_NBRS;              // this lane's row
        const float* erow = nbr + (size_t)irow * NBR_F;

        unsigned bofs = (unsigned)l * 16u;   // per-lane BF byte offset (opaque)

        // ---- pipeline warm-up ----
        u32x4 at0, at1, at0n, at1n;
        EBuf eb, ebn;
        int jn;
        {
            int j0 = idx[irow];
            at0 = *reinterpret_cast<const u32x4*>(abf + (size_t)j0 * 32 + g * 4);
            at1 = *reinterpret_cast<const u32x4*>(abf + (size_t)j0 * 32 + 16 + g * 4);
            eb = load_edges(erow, g);
        }
        jn = idx[irow + 1];

        #pragma unroll 1
        for (int m = 0; m < M_NBRS; ++m) {
            // ---- prefetch tile m+1 data, tile m+2 index ----
            if (m + 1 < M_NBRS) {
                at0n = *reinterpret_cast<const u32x4*>(abf + (size_t)jn * 32 + g * 4);
                at1n = *reinterpret_cast<const u32x4*>(abf + (size_t)jn * 32 + 16 + g * 4);
                ebn = load_edges(erow + (m + 1) * NBR_F, g);
                if (m + 2 < M_NBRS) jn = idx[irow + m + 2];
            }
            // ---- compute tile m ----
            asm volatile("" : "+v"(bofs));   // block LICM of B-fragment reads
            const char* bsb = reinterpret_cast<const char*>(BF);
            union { u32x4 u; short8 s; } a0, a1, a2, a3;
            a0.u = at0; a1.u = at1;
            a2.u[0] = eb.p2[0]; a2.u[1] = eb.p2[1]; a2.u[2] = eb.p2[2]; a2.u[3] = eb.p2[3];
            a3.u[0] = eb.p3[0]; a3.u[1] = eb.p3[1]; a3.u[2] = eb.p3[2]; a3.u[3] = eb.p3[3];
            #pragma unroll
            for (int p = 0; p < 4; ++p) {
                // self-term rides in as the accumulator init (pre-unpacked)
                f32x4 accf, accc;
                #pragma unroll
                for (int r4 = 0; r4 < 4; ++r4) {
                    accf[r4] = a1f[r4][p];
                    accc[r4] = a1c[r4][p];
                }
                #pragma unroll
                for (int kk = 0; kk < 4; ++kk) {
                    union { u32x4 u; short8 s; } uf, uc;
                    uf.u = *reinterpret_cast<const u32x4*>(
                        bsb + bofs + (unsigned)((p * 4 + kk) * 64 * 16));
                    uc.u = *reinterpret_cast<const u32x4*>(
                        bsb + bofs + (unsigned)(((p + 4) * 4 + kk) * 64 * 16));
                    short8 afk = (kk == 0) ? a0.s : (kk == 1) ? a1.s
                               : (kk == 2) ? a2.s : a3.s;
                    accf = __builtin_amdgcn_mfma_f32_16x16x32_bf16(afk, uf.s, accf, 0,0,0);
                    accc = __builtin_amdgcn_mfma_f32_16x16x32_bf16(afk, uc.s, accc, 0,0,0);
                }
                #pragma unroll
                for (int r4 = 0; r4 < 4; ++r4)
                    gs[r4][p] += sigmoid_f(accf[r4]) * softplus_f(accc[r4]);
            }
            // ---- rotate ----
            at0 = at0n; at1 = at1n; eb = ebn;
        }
        // ---- epilogue: x = atom + msg, store, accumulate BN partials ----
        #pragma unroll
        for (int r4 = 0; r4 < 4; ++r4) {
            int o = (base + g * 4 + r4) * ATOM_F + c;
            #pragma unroll
            for (int p = 0; p < 4; ++p) {
                float x = atom[o + p * 16] + gs[r4][p];
                X[o + p * 16] = x;
                sum_p[p] += x;
                sq_p[p] += x * x;
            }
        }
    }

    // ---- BN stats: wave reduce over g, block reduce over waves, 1 atomic ----
    #pragma unroll
    for (int p = 0; p < 4; ++p) {
        sum_p[p] += __shfl_xor(sum_p[p], 16, 64);
        sum_p[p] += __shfl_xor(sum_p[p], 32, 64);
        sq_p[p]  += __shfl_xor(sq_p[p], 16, 64);
        sq_p[p]  += __shfl_xor(sq_p[p], 32, 64);
    }
    __syncthreads();   // all waves done reading BF before reuse as scratch
    float* Rs = reinterpret_cast<float*>(BF);
    if (g == 0) {
        #pragma unroll
        for (int p = 0; p < 4; ++p) {
            Rs[w * 128 + p * 16 + c] = sum_p[p];
            Rs[512 + w * 128 + p * 16 + c] = sq_p[p];
        }
    }
    __syncthreads();
    if (tid < 128) {
        int q = tid & 63;
        int o = (tid >> 6) * 512;
        float v = Rs[o + q] + Rs[o + 128 + q] + Rs[o + 256 + q] + Rs[o + 384 + q];
        atomicAdd(&SUM[tid], v);
    }
}

// ---------------------------------------------------------------------------
// Final: derive BN scale/shift inline from SUM (L2-broadcast reads), then
// normalize + softplus in place.  (k_stats2 fused away: ~30 us launch
// overhead per kernel dominates the few redundant ops per thread.)
// ---------------------------------------------------------------------------
__global__ void k_final(float* __restrict__ X, const float* __restrict__ SUM,
                        const float* __restrict__ gamma, const float* __restrict__ beta)
{
    int q = blockIdx.x * 256 + threadIdx.x;   // exactly N*64/4 threads
    int fb = (q & 15);                         // float4 index within feature row
    const float4* S4 = reinterpret_cast<const float4*>(SUM);
    float4 s1 = S4[fb];            // sums for features fb*4..fb*4+3
    float4 s2 = S4[16 + fb];       // sq-sums
    float4 gm = reinterpret_cast<const float4*>(gamma)[fb];
    float4 bt = reinterpret_cast<const float4*>(beta)[fb];
    const float inv_n = 1.f / N_ATOMS;
    float4 x = reinterpret_cast<const float4*>(X)[q];
    float4 o;
    {
        float mean = s1.x * inv_n, msq = s2.x * inv_n;
        float sc = rsqrtf(msq - mean * mean + 1e-5f) * gm.x;
        o.x = softplus_f(x.x * sc + (bt.x - mean * sc));
    }
    {
        float mean = s1.y * inv_n, msq = s2.y * inv_n;
        float sc = rsqrtf(msq - mean * mean + 1e-5f) * gm.y;
        o.y = softplus_f(x.y * sc + (bt.y - mean * sc));
    }
    {
        float mean = s1.z * inv_n, msq = s2.z * inv_n;
        float sc = rsqrtf(msq - mean * mean + 1e-5f) * gm.z;
        o.z = softplus_f(x.z * sc + (bt.z - mean * sc));
    }
    {
        float mean = s1.w * inv_n, msq = s2.w * inv_n;
        float sc = rsqrtf(msq - mean * mean + 1e-5f) * gm.w;
        o.w = softplus_f(x.w * sc + (bt.w - mean * sc));
    }
    reinterpret_cast<float4*>(X)[q] = o;
}

extern "C" void kernel_launch(void* const* d_in, const int* in_sizes, int n_in,
                              void* d_out, int out_size, void* d_ws, size_t ws_size,
                              hipStream_t stream)
{
    const float* atom  = (const float*)d_in[0];
    const float* nbr   = (const float*)d_in[1];
    const float* W     = (const float*)d_in[2];
    const float* bias  = (const float*)d_in[3];
    const float* gamma = (const float*)d_in[4];
    const float* beta  = (const float*)d_in[5];
    const int*   idx   = (const int*)d_in[6];
    float* X = (float*)d_out;   // x pre-BN lives in d_out, finalized in place

    char* ws = (char*)d_ws;
    unsigned* abf = (unsigned*)ws;                                     // N*32 u32
    unsigned* A1P = (unsigned*)(ws + (size_t)N_ATOMS * 32 * 4);        // N_GROUPS*1024 u32
    float* SUM    = (float*)(ws + (size_t)N_ATOMS * 32 * 4
                                + (size_t)N_GROUPS * 1024 * 4);        // 128 f32

    const int blocks = (N_GROUPS + 3) / 4;   // 1563: one group per wave
    hipLaunchKernelGGL(k_prep,  dim3(blocks), dim3(256), 0, stream, atom, W, bias, abf, A1P, SUM);
    hipLaunchKernelGGL(k_msg,   dim3(blocks), dim3(256), 0, stream, atom, nbr, W, idx, abf, A1P, X, SUM);
    hipLaunchKernelGGL(k_final, dim3(6250),   dim3(256), 0, stream, X, SUM, gamma, beta);
}

// Round 7
// 423.533 us; speedup vs baseline: 1.2734x; 1.2734x over previous
//
#include <hip/hip_runtime.h>

#define N_ATOMS 100000
#define M_NBRS 12
#define ATOM_F 64
#define NBR_F 41
#define OUT_DIM 128   // 2*ATOM_F
#define IN_DIM 169    // 2*ATOM_F + NBR_F
#define N_GROUPS (N_ATOMS / 16)   // 6250, exact

typedef __attribute__((ext_vector_type(8))) short short8;
typedef __attribute__((ext_vector_type(4))) float f32x4;
typedef __attribute__((ext_vector_type(4))) unsigned u32x4;

// packed f32x2 -> bf16x2 (RNE): lo16 = bf16(a), hi16 = bf16(b). 1 VALU inst.
__device__ __forceinline__ unsigned cvt_pk(float a, float b) {
    unsigned r;
    asm("v_cvt_pk_bf16_f32 %0, %1, %2" : "=v"(r) : "v"(a), "v"(b));
    return r;
}
__device__ __forceinline__ float softplus_f(float x) {
    return fmaxf(x, 0.f) + __logf(1.f + __expf(-fabsf(x)));
}
__device__ __forceinline__ float sigmoid_f(float x) {
    return __fdividef(1.f, 1.f + __expf(-x));
}

// ---------------------------------------------------------------------------
// P: per-atom precompute, one 16-atom tile per wave, NO per-tile LDS.
//   abf[a*32 + kk*16 + g*4 + t] = bf16 pair (features kk*32+g*8+2t, +1)
//   A1P[grp*1024 + r4*256 + l*4 + nt] = u32{ lo=bf16((Wself·a+b)[nt*16+c]),
//        hi=bf16(...[64+nt*16+c]) } for row g*4+r4 — producer lane and
//        consumer lane are the SAME lane index -> both sides coalesced b128.
// W_self fragments staged frag-linear in LDS (16 KB, conflict-free).
// ---------------------------------------------------------------------------
__global__ __launch_bounds__(256, 4) void k_prep(
    const float* __restrict__ atom, const float* __restrict__ W,
    const float* __restrict__ bias, unsigned* __restrict__ abf_u32,
    unsigned* __restrict__ A1P, float* __restrict__ SUM)
{
    __shared__ __align__(16) unsigned BFp[16 * 64 * 4];   // 16 KB
    const int tid = threadIdx.x;
    const int w = tid >> 6, l = tid & 63;
    const int r = l & 15, g = l >> 4;

    if (blockIdx.x == 0 && tid < 128) SUM[tid] = 0.f;

    // stage W_self fragments: 16 frags x 64 lanes, 4 slots per thread
    #pragma unroll
    for (int s = 0; s < 4; ++s) {
        int f = s * 4 + w;              // frag = nt*2 + kk
        int nt = f >> 1, kk = f & 1;
        int col = nt * 16 + r;
        int kbase = kk * 32 + g * 8;
        const float* wp = W + col * IN_DIM + kbase;   // k < 64 always valid
        u32x4 pk;
        pk[0] = cvt_pk(wp[0], wp[1]); pk[1] = cvt_pk(wp[2], wp[3]);
        pk[2] = cvt_pk(wp[4], wp[5]); pk[3] = cvt_pk(wp[6], wp[7]);
        *reinterpret_cast<u32x4*>(&BFp[(f * 64 + l) * 4]) = pk;
    }
    __syncthreads();

    const int gw = blockIdx.x * 4 + w;
    if (gw >= N_GROUPS) return;
    const int base = gw * 16;

    float bb[8];
    #pragma unroll
    for (int nt = 0; nt < 8; ++nt) bb[nt] = bias[nt * 16 + r];

    // A fragments: 8 contiguous, 16B-aligned floats per (lane, kk)
    union { u32x4 u; short8 s; } af[2];
    #pragma unroll
    for (int kk = 0; kk < 2; ++kk) {
        const float4* ap = reinterpret_cast<const float4*>(atom)
                           + (size_t)(base + r) * 16 + kk * 8 + g * 2;
        float4 v0 = ap[0], v1 = ap[1];
        af[kk].u[0] = cvt_pk(v0.x, v0.y); af[kk].u[1] = cvt_pk(v0.z, v0.w);
        af[kk].u[2] = cvt_pk(v1.x, v1.y); af[kk].u[3] = cvt_pk(v1.z, v1.w);
        *reinterpret_cast<u32x4*>(&abf_u32[(size_t)(base + r) * 32 + kk * 16 + g * 4])
            = af[kk].u;
    }

    // MFMA: filter (nt) and core (nt+4), pack into A1P lane layout
    u32x4 outp[4];   // [r4][nt]
    #pragma unroll
    for (int nt = 0; nt < 4; ++nt) {
        f32x4 accf = {0.f,0.f,0.f,0.f}, accc = {0.f,0.f,0.f,0.f};
        #pragma unroll
        for (int kk = 0; kk < 2; ++kk) {
            union { u32x4 u; short8 s; } uf, uc;
            uf.u = *reinterpret_cast<const u32x4*>(&BFp[((nt * 2 + kk) * 64 + l) * 4]);
            uc.u = *reinterpret_cast<const u32x4*>(&BFp[(((nt + 4) * 2 + kk) * 64 + l) * 4]);
            accf = __builtin_amdgcn_mfma_f32_16x16x32_bf16(af[kk].s, uf.s, accf, 0,0,0);
            accc = __builtin_amdgcn_mfma_f32_16x16x32_bf16(af[kk].s, uc.s, accc, 0,0,0);
        }
        #pragma unroll
        for (int r4 = 0; r4 < 4; ++r4)
            outp[r4][nt] = cvt_pk(accf[r4] + bb[nt], accc[r4] + bb[nt + 4]);
    }
    #pragma unroll
    for (int r4 = 0; r4 < 4; ++r4)
        *reinterpret_cast<u32x4*>(&A1P[(size_t)gw * 1024 + r4 * 256 + l * 4]) = outp[r4];
}

// ---------------------------------------------------------------------------
// M: one 16-atom group per wave, 12 MFMA tiles (one per neighbor slot).
// A-fragments straight from global (no A-LDS; conflicts 0).  B fragments
// frag-linear in LDS (32 KB, conflict-free); opaque-asm blocks LICM.
// ROUND-7: launch_bounds(256,3).  Allocator evidence (r3/r4/r6): arch
// VGPRs = cap/2 (84/64/48) — the other half mirrors AGPRs.  (256,5)
// gave 48 VGPRs -> scratch spills (FETCH 567 MB, dur 301); (256,3)
// gives 84, fitting the live set PLUS a 2-deep gather pipeline: abf
// (12.8 MB) misses the 4 MB per-XCD L2, so gather latency is L3-class
// (~500-900 cyc) and the old 1-deep prefetch (~500 cyc cover at 3
// waves/SIMD) left misses exposed.  Edges stay 1-deep (sequential HBM
// stream).  a1q stays PACKED (16 regs; unpack at acc-init) — hoisting
// costs +16 live regs better spent on the pipeline.
// BN partial stats fused (128 atomics per block).
// ---------------------------------------------------------------------------
struct EBuf { unsigned p2[4]; unsigned p3[4]; };   // packed bf16 edge frags

__device__ __forceinline__ EBuf load_edges(const float* __restrict__ ep, int g)
{
    EBuf b;
    float v[8];
    #pragma unroll
    for (int j = 0; j < 8; ++j) v[j] = ep[g * 8 + j];      // floats 0..31
    b.p2[0] = cvt_pk(v[0], v[1]); b.p2[1] = cvt_pk(v[2], v[3]);
    b.p2[2] = cvt_pk(v[4], v[5]); b.p2[3] = cvt_pk(v[6], v[7]);
    b.p3[0] = b.p3[1] = b.p3[2] = b.p3[3] = 0u;
    if (g == 0) {
        float u[8];
        #pragma unroll
        for (int j = 0; j < 8; ++j) u[j] = ep[32 + j];     // floats 32..39
        b.p3[0] = cvt_pk(u[0], u[1]); b.p3[1] = cvt_pk(u[2], u[3]);
        b.p3[2] = cvt_pk(u[4], u[5]); b.p3[3] = cvt_pk(u[6], u[7]);
    } else if (g == 1) {
        b.p3[0] = cvt_pk(ep[40], 0.f);                     // float 40, pad 41
    }
    return b;
}

__global__ __launch_bounds__(256, 3) void k_msg(
    const float* __restrict__ atom, const float* __restrict__ nbr,
    const float* __restrict__ W, const int* __restrict__ idx,
    const unsigned* __restrict__ abf, const unsigned* __restrict__ A1P,
    float* __restrict__ X, float* __restrict__ SUM)
{
    __shared__ __align__(16) unsigned BF[32 * 64 * 4];   // 32 KB, frag-linear
    const int tid = threadIdx.x;
    const int w = tid >> 6, l = tid & 63;
    const int c = l & 15, g = l >> 4;

    // stage W_msg fragments: 32 frags x 64 lanes, 8 slots per thread.
    #pragma unroll
    for (int s = 0; s < 8; ++s) {
        int f = s * 4 + w;
        int nt = f >> 2, kk = f & 3;
        int col = nt * 16 + c;
        int kbase = kk * 32 + g * 8;
        const float* wp = W + col * IN_DIM + 64 + kbase;
        u32x4 pk;
        float v[8];
        #pragma unroll
        for (int j = 0; j < 8; ++j)
            v[j] = (kbase + j < 105) ? wp[j] : 0.f;        // K-pad 105..127
        pk[0] = cvt_pk(v[0], v[1]); pk[1] = cvt_pk(v[2], v[3]);
        pk[2] = cvt_pk(v[4], v[5]); pk[3] = cvt_pk(v[6], v[7]);
        *reinterpret_cast<u32x4*>(&BF[(f * 64 + l) * 4]) = pk;
    }
    __syncthreads();

    const int gw = blockIdx.x * 4 + w;
    float sum_p[4] = {0.f,0.f,0.f,0.f}, sq_p[4] = {0.f,0.f,0.f,0.f};

    if (gw < N_GROUPS) {
        const int base = gw * 16;
        // A1 packed pairs (coalesced b128); stays packed — 16 regs
        u32x4 a1q[4];
        #pragma unroll
        for (int r4 = 0; r4 < 4; ++r4)
            a1q[r4] = *reinterpret_cast<const u32x4*>(
                &A1P[(size_t)gw * 1024 + r4 * 256 + l * 4]);

        float gs[4][4];
        #pragma unroll
        for (int r4 = 0; r4 < 4; ++r4)
          #pragma unroll
          for (int p = 0; p < 4; ++p) gs[r4][p] = 0.f;

        const int irow = (base + c) * M_NBRS;              // this lane's row
        const float* erow = nbr + (size_t)irow * NBR_F;

        unsigned bofs = (unsigned)l * 16u;   // per-lane BF byte offset (opaque)

        // ---- 2-deep gather pipeline warm-up ----
        u32x4 ga0_0, ga0_1, ga1_0, ga1_1, ga2_0, ga2_1;
        EBuf eb, ebn;
        int jn;
        {
            int j0 = idx[irow + 0];
            int j1 = idx[irow + 1];
            ga0_0 = *reinterpret_cast<const u32x4*>(abf + (size_t)j0 * 32 + g * 4);
            ga0_1 = *reinterpret_cast<const u32x4*>(abf + (size_t)j0 * 32 + 16 + g * 4);
            ga1_0 = *reinterpret_cast<const u32x4*>(abf + (size_t)j1 * 32 + g * 4);
            ga1_1 = *reinterpret_cast<const u32x4*>(abf + (size_t)j1 * 32 + 16 + g * 4);
            eb = load_edges(erow, g);
            jn = idx[irow + 2];
        }

        #pragma unroll 1
        for (int m = 0; m < M_NBRS; ++m) {
            // ---- prefetch: edges m+1 (1-deep), gather m+2 (2-deep) ----
            if (m + 1 < M_NBRS)
                ebn = load_edges(erow + (m + 1) * NBR_F, g);
            if (m + 2 < M_NBRS) {
                ga2_0 = *reinterpret_cast<const u32x4*>(abf + (size_t)jn * 32 + g * 4);
                ga2_1 = *reinterpret_cast<const u32x4*>(abf + (size_t)jn * 32 + 16 + g * 4);
                if (m + 3 < M_NBRS) jn = idx[irow + m + 3];
            }
            // ---- compute tile m ----
            asm volatile("" : "+v"(bofs));   // block LICM of B-fragment reads
            const char* bsb = reinterpret_cast<const char*>(BF);
            union { u32x4 u; short8 s; } a0, a1, a2, a3;
            a0.u = ga0_0; a1.u = ga0_1;
            a2.u[0] = eb.p2[0]; a2.u[1] = eb.p2[1]; a2.u[2] = eb.p2[2]; a2.u[3] = eb.p2[3];
            a3.u[0] = eb.p3[0]; a3.u[1] = eb.p3[1]; a3.u[2] = eb.p3[2]; a3.u[3] = eb.p3[3];
            #pragma unroll
            for (int p = 0; p < 4; ++p) {
                // self-term rides in as the accumulator init (packed unpack)
                f32x4 accf, accc;
                #pragma unroll
                for (int r4 = 0; r4 < 4; ++r4) {
                    unsigned v = a1q[r4][p];
                    accf[r4] = __uint_as_float(v << 16);
                    accc[r4] = __uint_as_float(v & 0xffff0000u);
                }
                #pragma unroll
                for (int kk = 0; kk < 4; ++kk) {
                    union { u32x4 u; short8 s; } uf, uc;
                    uf.u = *reinterpret_cast<const u32x4*>(
                        bsb + bofs + (unsigned)((p * 4 + kk) * 64 * 16));
                    uc.u = *reinterpret_cast<const u32x4*>(
                        bsb + bofs + (unsigned)(((p + 4) * 4 + kk) * 64 * 16));
                    short8 afk = (kk == 0) ? a0.s : (kk == 1) ? a1.s
                               : (kk == 2) ? a2.s : a3.s;
                    accf = __builtin_amdgcn_mfma_f32_16x16x32_bf16(afk, uf.s, accf, 0,0,0);
                    accc = __builtin_amdgcn_mfma_f32_16x16x32_bf16(afk, uc.s, accc, 0,0,0);
                }
                #pragma unroll
                for (int r4 = 0; r4 < 4; ++r4)
                    gs[r4][p] += sigmoid_f(accf[r4]) * softplus_f(accc[r4]);
            }
            // ---- rotate pipeline (static names, rule-#20 safe) ----
            ga0_0 = ga1_0; ga0_1 = ga1_1;
            ga1_0 = ga2_0; ga1_1 = ga2_1;
            eb = ebn;
        }
        // ---- epilogue: x = atom + msg, store, accumulate BN partials ----
        #pragma unroll
        for (int r4 = 0; r4 < 4; ++r4) {
            int o = (base + g * 4 + r4) * ATOM_F + c;
            #pragma unroll
            for (int p = 0; p < 4; ++p) {
                float x = atom[o + p * 16] + gs[r4][p];
                X[o + p * 16] = x;
                sum_p[p] += x;
                sq_p[p] += x * x;
            }
        }
    }

    // ---- BN stats: wave reduce over g, block reduce over waves, 1 atomic ----
    #pragma unroll
    for (int p = 0; p < 4; ++p) {
        sum_p[p] += __shfl_xor(sum_p[p], 16, 64);
        sum_p[p] += __shfl_xor(sum_p[p], 32, 64);
        sq_p[p]  += __shfl_xor(sq_p[p], 16, 64);
        sq_p[p]  += __shfl_xor(sq_p[p], 32, 64);
    }
    __syncthreads();   // all waves done reading BF before reuse as scratch
    float* Rs = reinterpret_cast<float*>(BF);
    if (g == 0) {
        #pragma unroll
        for (int p = 0; p < 4; ++p) {
            Rs[w * 128 + p * 16 + c] = sum_p[p];
            Rs[512 + w * 128 + p * 16 + c] = sq_p[p];
        }
    }
    __syncthreads();
    if (tid < 128) {
        int q = tid & 63;
        int o = (tid >> 6) * 512;
        float v = Rs[o + q] + Rs[o + 128 + q] + Rs[o + 256 + q] + Rs[o + 384 + q];
        atomicAdd(&SUM[tid], v);
    }
}

// ---------------------------------------------------------------------------
// Final: derive BN scale/shift inline from SUM (L2-broadcast reads), then
// normalize + softplus in place.
// ---------------------------------------------------------------------------
__global__ void k_final(float* __restrict__ X, const float* __restrict__ SUM,
                        const float* __restrict__ gamma, const float* __restrict__ beta)
{
    int q = blockIdx.x * 256 + threadIdx.x;   // exactly N*64/4 threads
    int fb = (q & 15);                         // float4 index within feature row
    const float4* S4 = reinterpret_cast<const float4*>(SUM);
    float4 s1 = S4[fb];            // sums for features fb*4..fb*4+3
    float4 s2 = S4[16 + fb];       // sq-sums
    float4 gm = reinterpret_cast<const float4*>(gamma)[fb];
    float4 bt = reinterpret_cast<const float4*>(beta)[fb];
    const float inv_n = 1.f / N_ATOMS;
    float4 x = reinterpret_cast<const float4*>(X)[q];
    float4 o;
    {
        float mean = s1.x * inv_n, msq = s2.x * inv_n;
        float sc = rsqrtf(msq - mean * mean + 1e-5f) * gm.x;
        o.x = softplus_f(x.x * sc + (bt.x - mean * sc));
    }
    {
        float mean = s1.y * inv_n, msq = s2.y * inv_n;
        float sc = rsqrtf(msq - mean * mean + 1e-5f) * gm.y;
        o.y = softplus_f(x.y * sc + (bt.y - mean * sc));
    }
    {
        float mean = s1.z * inv_n, msq = s2.z * inv_n;
        float sc = rsqrtf(msq - mean * mean + 1e-5f) * gm.z;
        o.z = softplus_f(x.z * sc + (bt.z - mean * sc));
    }
    {
        float mean = s1.w * inv_n, msq = s2.w * inv_n;
        float sc = rsqrtf(msq - mean * mean + 1e-5f) * gm.w;
        o.w = softplus_f(x.w * sc + (bt.w - mean * sc));
    }
    reinterpret_cast<float4*>(X)[q] = o;
}

extern "C" void kernel_launch(void* const* d_in, const int* in_sizes, int n_in,
                              void* d_out, int out_size, void* d_ws, size_t ws_size,
                              hipStream_t stream)
{
    const float* atom  = (const float*)d_in[0];
    const float* nbr   = (const float*)d_in[1];
    const float* W     = (const float*)d_in[2];
    const float* bias  = (const float*)d_in[3];
    const float* gamma = (const float*)d_in[4];
    const float* beta  = (const float*)d_in[5];
    const int*   idx   = (const int*)d_in[6];
    float* X = (float*)d_out;   // x pre-BN lives in d_out, finalized in place

    char* ws = (char*)d_ws;
    unsigned* abf = (unsigned*)ws;                                     // N*32 u32
    unsigned* A1P = (unsigned*)(ws + (size_t)N_ATOMS * 32 * 4);        // N_GROUPS*1024 u32
    float* SUM    = (float*)(ws + (size_t)N_ATOMS * 32 * 4
                                + (size_t)N_GROUPS * 1024 * 4);        // 128 f32

    const int blocks = (N_GROUPS + 3) / 4;   // 1563: one group per wave
    hipLaunchKernelGGL(k_prep,  dim3(blocks), dim3(256), 0, stream, atom, W, bias, abf, A1P, SUM);
    hipLaunchKernelGGL(k_msg,   dim3(blocks), dim3(256), 0, stream, atom, nbr, W, idx, abf, A1P, X, SUM);
    hipLaunchKernelGGL(k_final, dim3(6250),   dim3(256), 0, stream, X, SUM, gamma, beta);
}

// Round 9
// 415.886 us; speedup vs baseline: 1.2968x; 1.0184x over previous
//
#include <hip/hip_runtime.h>

#define N_ATOMS 100000
#define M_NBRS 12
#define ATOM_F 64
#define NBR_F 41
#define OUT_DIM 128   // 2*ATOM_F
#define IN_DIM 169    // 2*ATOM_F + NBR_F
#define N_GROUPS (N_ATOMS / 16)   // 6250, exact
#define LOG2E 1.44269504f
#define LN2   0.69314718f

typedef __attribute__((ext_vector_type(8))) short short8;
typedef __attribute__((ext_vector_type(4))) float f32x4;
typedef __attribute__((ext_vector_type(4))) unsigned u32x4;

// packed f32x2 -> bf16x2 (RNE): lo16 = bf16(a), hi16 = bf16(b). 1 VALU inst.
__device__ __forceinline__ unsigned cvt_pk(float a, float b) {
    unsigned r;
    asm("v_cvt_pk_bf16_f32 %0, %1, %2" : "=v"(r) : "v"(a), "v"(b));
    return r;
}
// hardware transcendentals via BUILTINS (not inline asm): v_exp_f32 /
// v_log_f32 / v_rcp_f32 are VALU *trans* ops with a required wait-state
// before the consumer; the backend inserts it for intrinsics, but cannot
// see inside inline asm (round-8 NaN root cause).
__device__ __forceinline__ float fexp2(float x) { return __builtin_amdgcn_exp2f(x); }
__device__ __forceinline__ float flog2(float x) { return __builtin_amdgcn_logf(x); }
__device__ __forceinline__ float frcp(float x)  { return __builtin_amdgcn_rcpf(x); }
__device__ __forceinline__ float softplus_f(float x) {   // k_final only
    return fmaxf(x, 0.f) + __logf(1.f + __expf(-fabsf(x)));
}

// ---------------------------------------------------------------------------
// P: per-atom precompute, one 16-atom tile per wave, NO per-tile LDS.
//   abf[a]  : bf16 atom features, fragment layout (UNSCALED — A operand).
//   A1P     : y = LOG2E*(Wself·a + b), bf16 (filter,core) pairs in the
//             consumer's lane layout (same lane produces and consumes).
// LOG2E is folded into W and bias at staging so k_msg's activation can use
// raw exp2/log2 with no per-value scale muls.
// ---------------------------------------------------------------------------
__global__ __launch_bounds__(256, 4) void k_prep(
    const float* __restrict__ atom, const float* __restrict__ W,
    const float* __restrict__ bias, unsigned* __restrict__ abf_u32,
    unsigned* __restrict__ A1P, float* __restrict__ SUM)
{
    __shared__ __align__(16) unsigned BFp[16 * 64 * 4];   // 16 KB
    const int tid = threadIdx.x;
    const int w = tid >> 6, l = tid & 63;
    const int r = l & 15, g = l >> 4;

    if (blockIdx.x == 0 && tid < 128) SUM[tid] = 0.f;

    // stage W_self fragments (×LOG2E): 16 frags x 64 lanes, 4 per thread
    #pragma unroll
    for (int s = 0; s < 4; ++s) {
        int f = s * 4 + w;              // frag = nt*2 + kk
        int nt = f >> 1, kk = f & 1;
        int col = nt * 16 + r;
        int kbase = kk * 32 + g * 8;
        const float* wp = W + col * IN_DIM + kbase;   // k < 64 always valid
        u32x4 pk;
        pk[0] = cvt_pk(wp[0] * LOG2E, wp[1] * LOG2E);
        pk[1] = cvt_pk(wp[2] * LOG2E, wp[3] * LOG2E);
        pk[2] = cvt_pk(wp[4] * LOG2E, wp[5] * LOG2E);
        pk[3] = cvt_pk(wp[6] * LOG2E, wp[7] * LOG2E);
        *reinterpret_cast<u32x4*>(&BFp[(f * 64 + l) * 4]) = pk;
    }
    __syncthreads();

    const int gw = blockIdx.x * 4 + w;
    if (gw >= N_GROUPS) return;
    const int base = gw * 16;

    float bb[8];
    #pragma unroll
    for (int nt = 0; nt < 8; ++nt) bb[nt] = bias[nt * 16 + r] * LOG2E;

    // A fragments: 8 contiguous, 16B-aligned floats per (lane, kk) — UNSCALED
    union { u32x4 u; short8 s; } af[2];
    #pragma unroll
    for (int kk = 0; kk < 2; ++kk) {
        const float4* ap = reinterpret_cast<const float4*>(atom)
                           + (size_t)(base + r) * 16 + kk * 8 + g * 2;
        float4 v0 = ap[0], v1 = ap[1];
        af[kk].u[0] = cvt_pk(v0.x, v0.y); af[kk].u[1] = cvt_pk(v0.z, v0.w);
        af[kk].u[2] = cvt_pk(v1.x, v1.y); af[kk].u[3] = cvt_pk(v1.z, v1.w);
        *reinterpret_cast<u32x4*>(&abf_u32[(size_t)(base + r) * 32 + kk * 16 + g * 4])
            = af[kk].u;
    }

    // MFMA: filter (nt) and core (nt+4), pack into A1P lane layout
    u32x4 outp[4];   // [r4][nt]
    #pragma unroll
    for (int nt = 0; nt < 4; ++nt) {
        f32x4 accf = {0.f,0.f,0.f,0.f}, accc = {0.f,0.f,0.f,0.f};
        #pragma unroll
        for (int kk = 0; kk < 2; ++kk) {
            union { u32x4 u; short8 s; } uf, uc;
            uf.u = *reinterpret_cast<const u32x4*>(&BFp[((nt * 2 + kk) * 64 + l) * 4]);
            uc.u = *reinterpret_cast<const u32x4*>(&BFp[(((nt + 4) * 2 + kk) * 64 + l) * 4]);
            accf = __builtin_amdgcn_mfma_f32_16x16x32_bf16(af[kk].s, uf.s, accf, 0,0,0);
            accc = __builtin_amdgcn_mfma_f32_16x16x32_bf16(af[kk].s, uc.s, accc, 0,0,0);
        }
        #pragma unroll
        for (int r4 = 0; r4 < 4; ++r4)
            outp[r4][nt] = cvt_pk(accf[r4] + bb[nt], accc[r4] + bb[nt + 4]);
    }
    #pragma unroll
    for (int r4 = 0; r4 < 4; ++r4)
        *reinterpret_cast<u32x4*>(&A1P[(size_t)gw * 1024 + r4 * 256 + l * 4]) = outp[r4];
}

// ---------------------------------------------------------------------------
// M: one 16-atom group per wave, 12 MFMA tiles (one per neighbor slot).
// A-fragments straight from global; B fragments frag-linear in LDS (32 KB,
// conflict-free); opaque-asm blocks LICM of the B ds_reads.
// r3 (conflict-ridden) and r7 (clean) both landed ~185 us at ~2 waves/SIMD
// (reg total 160 -> occupancy step 128..256) — the wall is wave packing.
// So: (a) launch_bounds(256,4) = 128-reg step with the slim 1-deep
// pipeline; (b) activation floor cut via the LOG2E fold: y = z*log2e comes
// out of the MFMA, sigmoid = rcp(1+exp2(-y)), softplus = ln2*log2(1+exp2(y))
// — no scale muls, no abs/max guard (exp2 overflow needs z>88 = 60 sigma;
// threshold 0.17).  Trans ops via builtins (round-8 NaN: inline-asm hid the
// trans-use hazard from the backend).
// Spill alarm: WRITE_SIZE > 40 MB -> revert to (256,3) next round.
// BN partial stats fused (128 atomics per block).
// ---------------------------------------------------------------------------
struct EBuf { unsigned p2[4]; unsigned p3[4]; };   // packed bf16 edge frags

__device__ __forceinline__ EBuf load_edges(const float* __restrict__ ep, int g)
{
    EBuf b;
    f32x4 v0, v1;   // 16B loads at 4B alignment (dword-aligned, legal)
    __builtin_memcpy(&v0, ep + g * 8, 16);
    __builtin_memcpy(&v1, ep + g * 8 + 4, 16);
    b.p2[0] = cvt_pk(v0[0], v0[1]); b.p2[1] = cvt_pk(v0[2], v0[3]);
    b.p2[2] = cvt_pk(v1[0], v1[1]); b.p2[3] = cvt_pk(v1[2], v1[3]);
    b.p3[0] = b.p3[1] = b.p3[2] = b.p3[3] = 0u;
    if (g == 0) {
        f32x4 u0, u1;
        __builtin_memcpy(&u0, ep + 32, 16);
        __builtin_memcpy(&u1, ep + 36, 16);
        b.p3[0] = cvt_pk(u0[0], u0[1]); b.p3[1] = cvt_pk(u0[2], u0[3]);
        b.p3[2] = cvt_pk(u1[0], u1[1]); b.p3[3] = cvt_pk(u1[2], u1[3]);
    } else if (g == 1) {
        b.p3[0] = cvt_pk(ep[40], 0.f);                 // float 40, pad 41
    }
    return b;
}

__global__ __launch_bounds__(256, 4) void k_msg(
    const float* __restrict__ atom, const float* __restrict__ nbr,
    const float* __restrict__ W, const int* __restrict__ idx,
    const unsigned* __restrict__ abf, const unsigned* __restrict__ A1P,
    float* __restrict__ X, float* __restrict__ SUM)
{
    __shared__ __align__(16) unsigned BF[32 * 64 * 4];   // 32 KB, frag-linear
    const int tid = threadIdx.x;
    const int w = tid >> 6, l = tid & 63;
    const int c = l & 15, g = l >> 4;

    // stage W_msg fragments (×LOG2E): 32 frags x 64 lanes, 8 per thread
    #pragma unroll
    for (int s = 0; s < 8; ++s) {
        int f = s * 4 + w;
        int nt = f >> 2, kk = f & 3;
        int col = nt * 16 + c;
        int kbase = kk * 32 + g * 8;
        const float* wp = W + col * IN_DIM + 64 + kbase;
        u32x4 pk;
        float v[8];
        #pragma unroll
        for (int j = 0; j < 8; ++j)
            v[j] = (kbase + j < 105) ? wp[j] * LOG2E : 0.f;   // K-pad 105..127
        pk[0] = cvt_pk(v[0], v[1]); pk[1] = cvt_pk(v[2], v[3]);
        pk[2] = cvt_pk(v[4], v[5]); pk[3] = cvt_pk(v[6], v[7]);
        *reinterpret_cast<u32x4*>(&BF[(f * 64 + l) * 4]) = pk;
    }
    __syncthreads();

    const int gw = blockIdx.x * 4 + w;
    float sum_p[4] = {0.f,0.f,0.f,0.f}, sq_p[4] = {0.f,0.f,0.f,0.f};

    if (gw < N_GROUPS) {
        const int base = gw * 16;
        // A1 packed pairs (coalesced b128); stays packed — 16 regs
        u32x4 a1q[4];
        #pragma unroll
        for (int r4 = 0; r4 < 4; ++r4)
            a1q[r4] = *reinterpret_cast<const u32x4*>(
                &A1P[(size_t)gw * 1024 + r4 * 256 + l * 4]);

        float gs[4][4];
        #pragma unroll
        for (int r4 = 0; r4 < 4; ++r4)
          #pragma unroll
          for (int p = 0; p < 4; ++p) gs[r4][p] = 0.f;

        const int irow = (base + c) * M_NBRS;              // this lane's row
        const float* erow = nbr + (size_t)irow * NBR_F;

        unsigned bofs = (unsigned)l * 16u;   // per-lane BF byte offset (opaque)

        // ---- 1-deep pipeline warm-up ----
        u32x4 at0, at1, at0n, at1n;
        EBuf eb, ebn;
        int jn;
        {
            int j0 = idx[irow];
            at0 = *reinterpret_cast<const u32x4*>(abf + (size_t)j0 * 32 + g * 4);
            at1 = *reinterpret_cast<const u32x4*>(abf + (size_t)j0 * 32 + 16 + g * 4);
            eb = load_edges(erow, g);
        }
        jn = idx[irow + 1];

        #pragma unroll 1
        for (int m = 0; m < M_NBRS; ++m) {
            // ---- prefetch tile m+1 data, tile m+2 index ----
            if (m + 1 < M_NBRS) {
                at0n = *reinterpret_cast<const u32x4*>(abf + (size_t)jn * 32 + g * 4);
                at1n = *reinterpret_cast<const u32x4*>(abf + (size_t)jn * 32 + 16 + g * 4);
                ebn = load_edges(erow + (m + 1) * NBR_F, g);
                if (m + 2 < M_NBRS) jn = idx[irow + m + 2];
            }
            // ---- compute tile m ----
            asm volatile("" : "+v"(bofs));   // block LICM of B-fragment reads
            const char* bsb = reinterpret_cast<const char*>(BF);
            union { u32x4 u; short8 s; } a0, a1, a2, a3;
            a0.u = at0; a1.u = at1;
            a2.u[0] = eb.p2[0]; a2.u[1] = eb.p2[1]; a2.u[2] = eb.p2[2]; a2.u[3] = eb.p2[3];
            a3.u[0] = eb.p3[0]; a3.u[1] = eb.p3[1]; a3.u[2] = eb.p3[2]; a3.u[3] = eb.p3[3];
            #pragma unroll
            for (int p = 0; p < 4; ++p) {
                // self-term (already ×LOG2E) rides in as the accumulator init
                f32x4 accf, accc;
                #pragma unroll
                for (int r4 = 0; r4 < 4; ++r4) {
                    unsigned v = a1q[r4][p];
                    accf[r4] = __uint_as_float(v << 16);
                    accc[r4] = __uint_as_float(v & 0xffff0000u);
                }
                #pragma unroll
                for (int kk = 0; kk < 4; ++kk) {
                    union { u32x4 u; short8 s; } uf, uc;
                    uf.u = *reinterpret_cast<const u32x4*>(
                        bsb + bofs + (unsigned)((p * 4 + kk) * 64 * 16));
                    uc.u = *reinterpret_cast<const u32x4*>(
                        bsb + bofs + (unsigned)(((p + 4) * 4 + kk) * 64 * 16));
                    short8 afk = (kk == 0) ? a0.s : (kk == 1) ? a1.s
                               : (kk == 2) ? a2.s : a3.s;
                    accf = __builtin_amdgcn_mfma_f32_16x16x32_bf16(afk, uf.s, accf, 0,0,0);
                    accc = __builtin_amdgcn_mfma_f32_16x16x32_bf16(afk, uc.s, accc, 0,0,0);
                }
                // gate in y-space: sigmoid = rcp(1+2^-y), softplus = ln2*log2(1+2^y)
                #pragma unroll
                for (int r4 = 0; r4 < 4; ++r4) {
                    float sig = frcp(1.f + fexp2(-accf[r4]));
                    float sp  = flog2(1.f + fexp2(accc[r4])) * LN2;
                    gs[r4][p] += sig * sp;
                }
            }
            // ---- rotate ----
            at0 = at0n; at1 = at1n; eb = ebn;
        }
        // ---- epilogue: x = atom + msg, store, accumulate BN partials ----
        #pragma unroll
        for (int r4 = 0; r4 < 4; ++r4) {
            int o = (base + g * 4 + r4) * ATOM_F + c;
            #pragma unroll
            for (int p = 0; p < 4; ++p) {
                float x = atom[o + p * 16] + gs[r4][p];
                X[o + p * 16] = x;
                sum_p[p] += x;
                sq_p[p] += x * x;
            }
        }
    }

    // ---- BN stats: wave reduce over g, block reduce over waves, 1 atomic ----
    #pragma unroll
    for (int p = 0; p < 4; ++p) {
        sum_p[p] += __shfl_xor(sum_p[p], 16, 64);
        sum_p[p] += __shfl_xor(sum_p[p], 32, 64);
        sq_p[p]  += __shfl_xor(sq_p[p], 16, 64);
        sq_p[p]  += __shfl_xor(sq_p[p], 32, 64);
    }
    __syncthreads();   // all waves done reading BF before reuse as scratch
    float* Rs = reinterpret_cast<float*>(BF);
    if (g == 0) {
        #pragma unroll
        for (int p = 0; p < 4; ++p) {
            Rs[w * 128 + p * 16 + c] = sum_p[p];
            Rs[512 + w * 128 + p * 16 + c] = sq_p[p];
        }
    }
    __syncthreads();
    if (tid < 128) {
        int q = tid & 63;
        int o = (tid >> 6) * 512;
        float v = Rs[o + q] + Rs[o + 128 + q] + Rs[o + 256 + q] + Rs[o + 384 + q];
        atomicAdd(&SUM[tid], v);
    }
}

// ---------------------------------------------------------------------------
// Final: derive BN scale/shift inline from SUM (L2-broadcast reads), then
// normalize + softplus in place.
// ---------------------------------------------------------------------------
__global__ void k_final(float* __restrict__ X, const float* __restrict__ SUM,
                        const float* __restrict__ gamma, const float* __restrict__ beta)
{
    int q = blockIdx.x * 256 + threadIdx.x;   // exactly N*64/4 threads
    int fb = (q & 15);                         // float4 index within feature row
    const float4* S4 = reinterpret_cast<const float4*>(SUM);
    float4 s1 = S4[fb];            // sums for features fb*4..fb*4+3
    float4 s2 = S4[16 + fb];       // sq-sums
    float4 gm = reinterpret_cast<const float4*>(gamma)[fb];
    float4 bt = reinterpret_cast<const float4*>(beta)[fb];
    const float inv_n = 1.f / N_ATOMS;
    float4 x = reinterpret_cast<const float4*>(X)[q];
    float4 o;
    {
        float mean = s1.x * inv_n, msq = s2.x * inv_n;
        float sc = rsqrtf(msq - mean * mean + 1e-5f) * gm.x;
        o.x = softplus_f(x.x * sc + (bt.x - mean * sc));
    }
    {
        float mean = s1.y * inv_n, msq = s2.y * inv_n;
        float sc = rsqrtf(msq - mean * mean + 1e-5f) * gm.y;
        o.y = softplus_f(x.y * sc + (bt.y - mean * sc));
    }
    {
        float mean = s1.z * inv_n, msq = s2.z * inv_n;
        float sc = rsqrtf(msq - mean * mean + 1e-5f) * gm.z;
        o.z = softplus_f(x.z * sc + (bt.z - mean * sc));
    }
    {
        float mean = s1.w * inv_n, msq = s2.w * inv_n;
        float sc = rsqrtf(msq - mean * mean + 1e-5f) * gm.w;
        o.w = softplus_f(x.w * sc + (bt.w - mean * sc));
    }
    reinterpret_cast<float4*>(X)[q] = o;
}

extern "C" void kernel_launch(void* const* d_in, const int* in_sizes, int n_in,
                              void* d_out, int out_size, void* d_ws, size_t ws_size,
                              hipStream_t stream)
{
    const float* atom  = (const float*)d_in[0];
    const float* nbr   = (const float*)d_in[1];
    const float* W     = (const float*)d_in[2];
    const float* bias  = (const float*)d_in[3];
    const float* gamma = (const float*)d_in[4];
    const float* beta  = (const float*)d_in[5];
    const int*   idx   = (const int*)d_in[6];
    float* X = (float*)d_out;   // x pre-BN lives in d_out, finalized in place

    char* ws = (char*)d_ws;
    unsigned* abf = (unsigned*)ws;                                     // N*32 u32
    unsigned* A1P = (unsigned*)(ws + (size_t)N_ATOMS * 32 * 4);        // N_GROUPS*1024 u32
    float* SUM    = (float*)(ws + (size_t)N_ATOMS * 32 * 4
                                + (size_t)N_GROUPS * 1024 * 4);        // 128 f32

    const int blocks = (N_GROUPS + 3) / 4;   // 1563: one group per wave
    hipLaunchKernelGGL(k_prep,  dim3(blocks), dim3(256), 0, stream, atom, W, bias, abf, A1P, SUM);
    hipLaunchKernelGGL(k_msg,   dim3(blocks), dim3(256), 0, stream, atom, nbr, W, idx, abf, A1P, X, SUM);
    hipLaunchKernelGGL(k_final, dim3(6250),   dim3(256), 0, stream, X, SUM, gamma, beta);
}